// Round 5
// baseline (87.095 us; speedup 1.0000x reference)
//
#include <hip/hip_runtime.h>

#define HIDDEN  128
#define N_NODES 100000
#define N_EDGES 2000000
#define NBLK    512
#define NTHR    256

typedef float f32x4 __attribute__((ext_vector_type(4)));
typedef int   i32x4 __attribute__((ext_vector_type(4)));

// Fused: phase 1 computes per-node dot products into tables in d_ws,
// software grid barrier (all 512 blocks resident: 2 blocks/CU), phase 2
// gathers the tables per edge. Barrier counter is memset to 0 on the
// stream before each launch (graph-capture-safe, deterministic).
__global__ __launch_bounds__(NTHR) void fused_edge_decoder(
    const float* __restrict__ x_src,
    const float* __restrict__ x_dst,
    const int*   __restrict__ idx,     // [2*N_EDGES]
    const float* __restrict__ w,       // [256]
    const float* __restrict__ bias,    // [1]
    float* __restrict__ out,           // [N_EDGES]
    float* __restrict__ s_tab,         // [N_NODES]   (in d_ws)
    float* __restrict__ d_tab,         // [N_NODES]   (in d_ws)
    int*   __restrict__ barrier_ct)    // [1]         (in d_ws, pre-zeroed)
{
    const int tid      = blockIdx.x * NTHR + threadIdx.x;  // 0 .. 131071
    const int nthreads = NBLK * NTHR;                      // 131072
    const int lane     = tid & 15;

    // ---------------- Phase 1: per-node dots ----------------
    // 16 lanes per node, each lane covers 8 of 128 floats (2x float4).
    const f32x4* wv = reinterpret_cast<const f32x4*>(w);
    const f32x4 ws0 = wv[lane];
    const f32x4 ws1 = wv[lane + 16];
    const f32x4 wd0 = wv[lane + 32];
    const f32x4 wd1 = wv[lane + 48];

    const int group   = tid >> 4;        // 0 .. 8191
    const int ngroups = nthreads >> 4;   // 8192

    #pragma unroll 2
    for (int node = group; node < N_NODES; node += ngroups) {
        const f32x4* xs = reinterpret_cast<const f32x4*>(x_src + (size_t)node * HIDDEN);
        const f32x4* xd = reinterpret_cast<const f32x4*>(x_dst + (size_t)node * HIDDEN);
        const f32x4 a0 = __builtin_nontemporal_load(xs + lane);
        const f32x4 a1 = __builtin_nontemporal_load(xs + lane + 16);
        const f32x4 b0 = __builtin_nontemporal_load(xd + lane);
        const f32x4 b1 = __builtin_nontemporal_load(xd + lane + 16);

        float ss = a0.x*ws0.x + a0.y*ws0.y + a0.z*ws0.z + a0.w*ws0.w
                 + a1.x*ws1.x + a1.y*ws1.y + a1.z*ws1.z + a1.w*ws1.w;
        float dd = b0.x*wd0.x + b0.y*wd0.y + b0.z*wd0.z + b0.w*wd0.w
                 + b1.x*wd1.x + b1.y*wd1.y + b1.z*wd1.z + b1.w*wd1.w;

        #pragma unroll
        for (int off = 8; off; off >>= 1) {
            ss += __shfl_xor(ss, off);
            dd += __shfl_xor(dd, off);
        }
        if (lane == 0) {
            s_tab[node] = ss;
            d_tab[node] = dd;
        }
    }

    // ---------------- Grid-wide barrier ----------------
    __syncthreads();
    if (threadIdx.x == 0) {
        // Release our table writes at device scope, count in, spin.
        __hip_atomic_fetch_add(barrier_ct, 1, __ATOMIC_RELEASE, __HIP_MEMORY_SCOPE_AGENT);
        while (__hip_atomic_load(barrier_ct, __ATOMIC_ACQUIRE, __HIP_MEMORY_SCOPE_AGENT) < NBLK) {
            __builtin_amdgcn_s_sleep(1);
        }
    }
    __syncthreads();

    // ---------------- Phase 2: per-edge gather ----------------
    const float bv = bias[0];
    const i32x4* ia = reinterpret_cast<const i32x4*>(idx);
    const i32x4* ib = reinterpret_cast<const i32x4*>(idx + N_EDGES);
    f32x4* ov = reinterpret_cast<f32x4*>(out);
    const int nt = N_EDGES / 8;          // 250000 threads-worth, 8 edges each

    for (int t = tid; t < nt; t += nthreads) {
        const i32x4 a0 = __builtin_nontemporal_load(ia + 2 * t);
        const i32x4 a1 = __builtin_nontemporal_load(ia + 2 * t + 1);
        const i32x4 b0 = __builtin_nontemporal_load(ib + 2 * t);
        const i32x4 b1 = __builtin_nontemporal_load(ib + 2 * t + 1);

        f32x4 o0, o1;
        o0.x = s_tab[a0.x] + d_tab[b0.x] + bv;
        o0.y = s_tab[a0.y] + d_tab[b0.y] + bv;
        o0.z = s_tab[a0.z] + d_tab[b0.z] + bv;
        o0.w = s_tab[a0.w] + d_tab[b0.w] + bv;
        o1.x = s_tab[a1.x] + d_tab[b1.x] + bv;
        o1.y = s_tab[a1.y] + d_tab[b1.y] + bv;
        o1.z = s_tab[a1.z] + d_tab[b1.z] + bv;
        o1.w = s_tab[a1.w] + d_tab[b1.w] + bv;

        __builtin_nontemporal_store(o0, ov + 2 * t);
        __builtin_nontemporal_store(o1, ov + 2 * t + 1);
    }
}

extern "C" void kernel_launch(void* const* d_in, const int* in_sizes, int n_in,
                              void* d_out, int out_size, void* d_ws, size_t ws_size,
                              hipStream_t stream) {
    const float* x_src = (const float*)d_in[0];
    const float* x_dst = (const float*)d_in[1];
    const int*   idx   = (const int*)d_in[2];
    const float* w     = (const float*)d_in[3];
    const float* bias  = (const float*)d_in[4];
    float* out = (float*)d_out;

    float* s_tab = (float*)d_ws;
    float* d_tab = s_tab + N_NODES;
    int*   barrier_ct = (int*)(d_tab + N_NODES);

    // Reset the barrier counter every call (deterministic across graph replays).
    hipMemsetAsync(barrier_ct, 0, sizeof(int), stream);

    fused_edge_decoder<<<NBLK, NTHR, 0, stream>>>(
        x_src, x_dst, idx, w, bias, out, s_tab, d_tab, barrier_ct);
}